// Round 11
// baseline (24408.875 us; speedup 1.0000x reference)
//
#include <hip/hip_runtime.h>

#define B_SZ   256
#define T_SZ   128
#define IN_DIM 512
#define EMB    1024
#define HID    1024
#define G4     4096
#define NCLS   10
#define PSTR   2560   // A-plane row stride (shorts): [x 512 | h0 1024 | h1 1024]
#define NBLK   512    // 512 blocks x 256 threads (4 waves), 2 blocks/CU

typedef __attribute__((ext_vector_type(8))) short short8v;
typedef __attribute__((ext_vector_type(4))) float floatx4;

__device__ __forceinline__ unsigned short bf16hi(float f) {
    union { float f; unsigned u; } v; v.f = f;
    unsigned r = v.u + 0x7fff + ((v.u >> 16) & 1);   // RNE
    return (unsigned short)(r >> 16);
}
__device__ __forceinline__ float bf2f(unsigned short b) {
    union { unsigned u; float f; } v; v.u = ((unsigned)b) << 16;
    return v.f;
}

// ---------------------------------------------------------------------------
// fp32 vector GEMM (setup only): C[M,N] = A[M,K] @ B[K,N]
// ---------------------------------------------------------------------------
template<int BM,int BN,int BK,int TM,int TN>
__global__ __launch_bounds__((BM/TM)*(BN/TN))
void gemm_f32_nn(const float* __restrict__ A, const float* __restrict__ Bm,
                 float* __restrict__ C, int M, int N, int K) {
    constexpr int THREADS = (BM/TM)*(BN/TN);
    __shared__ float As[BK][BM+4];
    __shared__ float Bs[BK][BN+4];
    const int tid  = threadIdx.x;
    const int tcol = tid % (BN/TN);
    const int trow = tid / (BN/TN);
    const int bm   = blockIdx.y * BM;
    const int bn   = blockIdx.x * BN;
    float acc[TM][TN];
#pragma unroll
    for (int i = 0; i < TM; ++i)
#pragma unroll
        for (int j = 0; j < TN; ++j) acc[i][j] = 0.f;
    for (int k0 = 0; k0 < K; k0 += BK) {
#pragma unroll
        for (int r = 0; r < BM*BK/4; r += THREADS) {
            int i  = r + tid;
            int m  = i / (BK/4);
            int kk = (i % (BK/4)) * 4;
            const float4 v = *(const float4*)(&A[(size_t)(bm+m)*K + k0 + kk]);
            As[kk+0][m]=v.x; As[kk+1][m]=v.y; As[kk+2][m]=v.z; As[kk+3][m]=v.w;
        }
#pragma unroll
        for (int r = 0; r < BK*BN/4; r += THREADS) {
            int i  = r + tid;
            int kk = i / (BN/4);
            int n4 = (i % (BN/4)) * 4;
            const float4 v = *(const float4*)(&Bm[(size_t)(k0+kk)*N + bn + n4]);
            *(float4*)(&Bs[kk][n4]) = v;
        }
        __syncthreads();
#pragma unroll
        for (int k = 0; k < BK; ++k) {
            float a[TM], b[TN];
#pragma unroll
            for (int i = 0; i < TM; ++i) a[i] = As[k][trow*TM+i];
#pragma unroll
            for (int j = 0; j < TN; ++j) b[j] = Bs[k][tcol*TN+j];
#pragma unroll
            for (int i = 0; i < TM; ++i)
#pragma unroll
                for (int j = 0; j < TN; ++j) acc[i][j] += a[i]*b[j];
        }
        __syncthreads();
    }
#pragma unroll
    for (int i = 0; i < TM; ++i)
#pragma unroll
        for (int j = 0; j < TN; ++j)
            C[(size_t)(bm+trow*TM+i)*N + bn + tcol*TN + j] = acc[i][j];
}

// ---------------------------------------------------------------------------
// Weight swizzle to frag-major hi/lo, gate-interleaved columns.
// Output col n (0..4095): unit j=n>>2, gate q=n&3 -> source row q*1024 + j.
// K split: kf < kf0 from M0 (width K0), else from M1 (width K1).
// frag (cf, kf): dst[((cf*kfcnt+kf)*2+p)*512 + l*8 + j]  (cf = 16-col stripe)
// ---------------------------------------------------------------------------
__global__ void swz2(const float* __restrict__ M0, int K0, int kf0,
                     const float* __restrict__ M1, int K1, int kfcnt,
                     unsigned short* __restrict__ dst) {
    int gid = blockIdx.x * 256 + threadIdx.x;
    int l   = gid & 63;
    int kf  = (gid >> 6) % kfcnt;
    int cf  = gid / (64 * kfcnt);
    int n   = cf*16 + (l & 15);
    int row = ((n & 3) << 10) + (n >> 2);
    const float* src; int kk = (l >> 4) * 8;
    if (kf < kf0) { src = M0 + (size_t)row * K0; kk += kf * 32; }
    else          { src = M1 + (size_t)row * K1; kk += (kf - kf0) * 32; }
    short8v vh, vl;
#pragma unroll
    for (int j = 0; j < 8; ++j) {
        float f = src[kk + j];
        unsigned short h = bf16hi(f);
        vh[j] = (short)h;
        vl[j] = (short)bf16hi(f - bf2f(h));
    }
    size_t base = ((size_t)(cf * kfcnt + kf) * 2) * 512 + (size_t)l * 8;
    *(short8v*)(dst + base)       = vh;
    *(short8v*)(dst + base + 512) = vl;
}

// bcombI[4j+q] = b_ih0 + b_hh0 + W_ih0[row,:] . b_enc   (row = q*1024+j)
__global__ void build_bcombI(const float* __restrict__ W_ih0, const float* __restrict__ b_enc,
                             const float* __restrict__ b_ih0, const float* __restrict__ b_hh0,
                             float* __restrict__ bcombI) {
    int row  = blockIdx.x * 4 + (threadIdx.x >> 6);
    int lane = threadIdx.x & 63;
    const float* w = W_ih0 + (size_t)row * EMB;
    float s = 0.f;
    for (int k = lane; k < EMB; k += 64) s += w[k] * b_enc[k];
#pragma unroll
    for (int o = 32; o > 0; o >>= 1) s += __shfl_down(s, o);
    if (lane == 0) {
        int n = ((row & 1023) << 2) | (row >> 10);
        bcombI[n] = s + b_ih0[row] + b_hh0[row];
    }
}

__global__ void addvI(const float* __restrict__ a, const float* __restrict__ b,
                      float* __restrict__ o) {
    int i = blockIdx.x * 256 + threadIdx.x;
    int n = ((i & 1023) << 2) | (i >> 10);
    o[n] = a[i] + b[i];
}

// ---------------------------------------------------------------------------
// Persistent LSTM, register-resident weights (persistent-RNN style).
// 512 blocks x 256 threads (4 waves), 2 blocks/CU.
//   bid < 256 : LEFT  = gates0(t), cols 16*bid.., K=1536 (x|h0), 48 kf
//   bid >= 256: RIGHT = gates1(t-1), cols 16*(bid-256).., K=2048 (h0|h1), 64 kf
// Block = 256 rows x 16 cols. Wave w owns kf range [w*NKF,(w+1)*NKF) and holds
// its B-fragments in registers (loaded ONCE — zero weight traffic per phase).
// K-loop: fully unrolled (static reg indices), A global->reg streaming,
// no LDS staging, no intra-K barriers. 4-wave partial sum via gacc LDS,
// then in-block LSTM cell (c-state in regs, 4 cells/thread).
// One grid barrier per phase; planes parity-double-buffered.
// ---------------------------------------------------------------------------
__device__ __forceinline__ void gridbar(unsigned* bar, unsigned target, int tid) {
    __syncthreads();
    if (tid == 0) {
        __threadfence();
        atomicAdd(bar, 1u);
        while (__hip_atomic_load(bar, __ATOMIC_RELAXED, __HIP_MEMORY_SCOPE_AGENT) < target)
            __builtin_amdgcn_s_sleep(1);
        __threadfence();
    }
    __syncthreads();
}

__device__ __forceinline__ void store_xz(unsigned short* ph, unsigned short* pl,
                                         int bid, int tid, float2 xv) {
    unsigned short h0 = bf16hi(xv.x), h1 = bf16hi(xv.y);
    ushort2 hh; hh.x = h0; hh.y = h1;
    ushort2 lv; lv.x = bf16hi(xv.x - bf2f(h0)); lv.y = bf16hi(xv.y - bf2f(h1));
    size_t o = (size_t)bid * PSTR + tid * 2;
    *(ushort2*)(ph + o) = hh;
    *(ushort2*)(pl + o) = lv;
}

template<int NKF, int KFCNT>
__device__ __forceinline__ void run_chain(
        const float* __restrict__ x,
        const unsigned short* __restrict__ Bz,
        const float* __restrict__ biasI,
        unsigned short* p0h, unsigned short* p0l,
        unsigned short* p1h, unsigned short* p1l,
        const int acol0, const int hcol0, const int cf, const bool is_left,
        float* smem, unsigned* bar, unsigned target, const int tid, const int bid) {
    const int w = tid >> 6, l = tid & 63;
    const int kbase = w * NKF;

    // --- load this wave's weight fragments into registers (once) ---
    short8v wr[2*NKF];
#pragma unroll
    for (int i = 0; i < NKF; ++i) {
        size_t fo = ((size_t)(cf * KFCNT + kbase + i) * 2) * 512 + (size_t)l * 8;
        wr[2*i]   = *(const short8v*)(Bz + fo);
        wr[2*i+1] = *(const short8v*)(Bz + fo + 512);
    }
    const float biasv = (w == 0) ? biasI[cf*16 + (l & 15)] : 0.f;

    unsigned short* PH[2] = {p0h, p1h};
    unsigned short* PL[2] = {p0l, p1l};
    float (*gacc)[256][16] = (float (*)[256][16])smem;

    float cst[4] = {0.f, 0.f, 0.f, 0.f};
    const int cu = tid & 3, rq = tid >> 2;       // cell: unit cu, rows rq*4..+3
    const size_t abase0 = (size_t)(l & 15) * PSTR + acol0 + kbase*32 + ((l >> 4) * 8);

    for (int t = 0; t <= T_SZ; ++t) {
        const int cur = t & 1, nxt = cur ^ 1;
        const bool conv = (t < T_SZ - 1) && (bid < B_SZ);
        float2 xv;
        if (conv) xv = *(const float2*)&x[((size_t)bid * T_SZ + t + 1) * IN_DIM + tid * 2];

        const bool active = is_left ? (t < T_SZ) : (t >= 1);
        if (active) {
            const unsigned short* ph  = PH[cur];
            const unsigned short* plo = PL[cur];

            floatx4 acc[16];
#pragma unroll
            for (int m = 0; m < 16; ++m) acc[m] = (floatx4){biasv, biasv, biasv, biasv};

            // fully-unrolled K loop: A streams global->reg, B from registers
#pragma unroll
            for (int i = 0; i < NKF; ++i) {
#pragma unroll
                for (int m = 0; m < 16; ++m) {
                    size_t o = abase0 + (size_t)(m*16) * PSTR + i*32;
                    short8v ah = *(const short8v*)(ph + o);
                    short8v al = *(const short8v*)(plo + o);
                    acc[m] = __builtin_amdgcn_mfma_f32_16x16x32_bf16(ah, wr[2*i],   acc[m], 0, 0, 0);
                    acc[m] = __builtin_amdgcn_mfma_f32_16x16x32_bf16(ah, wr[2*i+1], acc[m], 0, 0, 0);
                    acc[m] = __builtin_amdgcn_mfma_f32_16x16x32_bf16(al, wr[2*i],   acc[m], 0, 0, 0);
                }
            }

            // publish wave partials to LDS (C/D layout: col=lane&15, row=(lane>>4)*4+j)
#pragma unroll
            for (int m = 0; m < 16; ++m) {
                int rb = m*16 + ((l >> 4) * 4);
#pragma unroll
                for (int j = 0; j < 4; ++j)
                    gacc[w][rb + j][l & 15] = acc[m][j];
            }
            __syncthreads();

            // LSTM cell: 4 units x 256 rows per block; thread = unit cu, 4 rows
            {
                unsigned short* nh = PH[nxt];
                unsigned short* nl = PL[nxt];
#pragma unroll
                for (int i = 0; i < 4; ++i) {
                    int r = rq*4 + i;
                    floatx4 g = *(const floatx4*)&gacc[0][r][4*cu];
                    g += *(const floatx4*)&gacc[1][r][4*cu];
                    g += *(const floatx4*)&gacc[2][r][4*cu];
                    g += *(const floatx4*)&gacc[3][r][4*cu];
                    float ii = 1.f / (1.f + expf(-g[0]));
                    float ff = 1.f / (1.f + expf(-g[1]));
                    float gg = tanhf(g[2]);
                    float oo = 1.f / (1.f + expf(-g[3]));
                    float cn = ff * cst[i] + ii * gg;
                    cst[i] = cn;
                    float h = oo * tanhf(cn);
                    unsigned short hh = bf16hi(h);
                    size_t o = (size_t)r * PSTR + hcol0 + cf*4 + cu;
                    nh[o] = hh;
                    nl[o] = bf16hi(h - bf2f(hh));
                }
            }
        }

        if (conv) store_xz(PH[nxt], PL[nxt], bid, tid, xv);
        target += NBLK; gridbar(bar, target, tid);
    }
}

__global__ __launch_bounds__(256, 2)
void lstm_persist(const float* __restrict__ x,
                  const unsigned short* __restrict__ WLz,
                  const unsigned short* __restrict__ WRz,
                  const float* __restrict__ biasLI, const float* __restrict__ biasRI,
                  unsigned short* __restrict__ p0h, unsigned short* __restrict__ p0l,
                  unsigned short* __restrict__ p1h, unsigned short* __restrict__ p1l,
                  const float* __restrict__ Wcls, const float* __restrict__ bcls,
                  float* __restrict__ out, unsigned* __restrict__ bar) {
    __shared__ float smem[4 * 256 * 16];             // gacc, 64 KB

    const int tid = threadIdx.x, bid = blockIdx.x;

    // prologue: stage x(0) into plane 0 (bid == batch row)
    if (bid < B_SZ) {
        float2 xv = *(const float2*)&x[((size_t)bid * T_SZ) * IN_DIM + tid * 2];
        store_xz(p0h, p0l, bid, tid, xv);
    }
    gridbar(bar, NBLK, tid);

    const int cf = bid & 255;
    if (bid < 256)
        run_chain<12, 48>(x, WLz, biasLI, p0h, p0l, p1h, p1l,
                          0, 512, cf, true, smem, bar, NBLK, tid, bid);
    else
        run_chain<16, 64>(x, WRz, biasRI, p0h, p0l, p1h, p1l,
                          512, 1536, cf, false, smem, bar, NBLK, tid, bid);

    // classifier: blocks 0..255 -> batch row bid; h1 = plane[(T+1)&1]
    if (bid < B_SZ) {
        const unsigned short* hh = ((T_SZ + 1) & 1) ? p1h : p0h;
        const unsigned short* hl = ((T_SZ + 1) & 1) ? p1l : p0l;
        float part[NCLS];
#pragma unroll
        for (int n = 0; n < NCLS; ++n) part[n] = 0.f;
        for (int k = tid; k < HID; k += 256) {
            size_t o = (size_t)bid * PSTR + 1536 + k;
            float hv = bf2f(hh[o]) + bf2f(hl[o]);
#pragma unroll
            for (int n = 0; n < NCLS; ++n) part[n] += hv * Wcls[(size_t)n * HID + k];
        }
        float* red = smem;
        for (int n = 0; n < NCLS; ++n) {
            red[tid] = part[n];
            __syncthreads();
            for (int s = 128; s > 0; s >>= 1) {
                if (tid < s) red[tid] += red[tid + s];
                __syncthreads();
            }
            if (tid == 0) out[(size_t)bid * NCLS + n] = red[0] + bcls[n];
            __syncthreads();
        }
    }
}

extern "C" void kernel_launch(void* const* d_in, const int* in_sizes, int n_in,
                              void* d_out, int out_size, void* d_ws, size_t ws_size,
                              hipStream_t stream) {
    const float* x      = (const float*)d_in[0];
    const float* W_enc  = (const float*)d_in[1];
    const float* b_enc  = (const float*)d_in[2];
    const float* W_ih0  = (const float*)d_in[3];
    const float* W_hh0  = (const float*)d_in[4];
    const float* b_ih0  = (const float*)d_in[5];
    const float* b_hh0  = (const float*)d_in[6];
    const float* W_ih1  = (const float*)d_in[7];
    const float* W_hh1  = (const float*)d_in[8];
    const float* b_ih1  = (const float*)d_in[9];
    const float* b_hh1  = (const float*)d_in[10];
    const float* W_cls  = (const float*)d_in[11];
    const float* b_cls  = (const float*)d_in[12];
    float* out = (float*)d_out;

    float* ws = (float*)d_ws;
    size_t off = 0;
    unsigned short* WLz    = (unsigned short*)(ws + off); off += (size_t)G4 * 1536 * 2 / 2;
    unsigned short* WRz    = (unsigned short*)(ws + off); off += (size_t)G4 * 2048 * 2 / 2;
    float*          Wcomb  = ws + off;                    off += (size_t)G4 * IN_DIM;
    float*          biasLI = ws + off;                    off += G4;
    float*          biasRI = ws + off;                    off += G4;
    unsigned short* planes = (unsigned short*)(ws + off); off += (size_t)4 * B_SZ * PSTR / 2;
    unsigned*       bar    = (unsigned*)(ws + off);       off += 64;

    unsigned short* p0h = planes;
    unsigned short* p0l = p0h + (size_t)B_SZ * PSTR;
    unsigned short* p1h = p0l + (size_t)B_SZ * PSTR;
    unsigned short* p1l = p1h + (size_t)B_SZ * PSTR;

    // --- setup ---
    gemm_f32_nn<128,128,16,8,8><<<dim3(IN_DIM/128, G4/128), 256, 0, stream>>>(
        W_ih0, W_enc, Wcomb, G4, IN_DIM, EMB);
    build_bcombI<<<G4/4, 256, 0, stream>>>(W_ih0, b_enc, b_ih0, b_hh0, biasLI);
    addvI<<<G4/256, 256, 0, stream>>>(b_ih1, b_hh1, biasRI);
    // WLz: [Wcomb(16 kf) | W_hh0(32 kf)] ; WRz: [W_ih1(32 kf) | W_hh1(32 kf)]
    swz2<<<256*48/4, 256, 0, stream>>>(Wcomb, IN_DIM, 16, W_hh0, HID, 48, WLz);
    swz2<<<256*64/4, 256, 0, stream>>>(W_ih1, HID, 32, W_hh1, HID, 64, WRz);
    hipMemsetAsync(planes, 0, (size_t)4 * B_SZ * PSTR * 2, stream);
    hipMemsetAsync(bar, 0, 64 * sizeof(unsigned), stream);

    // --- the whole recurrence in one kernel ---
    lstm_persist<<<NBLK, 256, 0, stream>>>(
        x, WLz, WRz, biasLI, biasRI,
        p0h, p0l, p1h, p1l, W_cls, b_cls, out, bar);
}

// Round 12
// 12453.250 us; speedup vs baseline: 1.9600x; 1.9600x over previous
//
#include <hip/hip_runtime.h>

#define B_SZ   256
#define T_SZ   128
#define IN_DIM 512
#define EMB    1024
#define HID    1024
#define G4     4096
#define NCLS   10
#define PSTR   2560   // A-plane row stride (shorts): [x 512 | h0 1024 | h1 1024]
#define NBLK   512    // 512 blocks x 256 threads (4 waves), 2 independent blocks/CU

typedef __attribute__((ext_vector_type(8))) short short8v;
typedef __attribute__((ext_vector_type(4))) float floatx4;

__device__ __forceinline__ unsigned short bf16hi(float f) {
    union { float f; unsigned u; } v; v.f = f;
    unsigned r = v.u + 0x7fff + ((v.u >> 16) & 1);   // RNE
    return (unsigned short)(r >> 16);
}
__device__ __forceinline__ float bf2f(unsigned short b) {
    union { unsigned u; float f; } v; v.u = ((unsigned)b) << 16;
    return v.f;
}

// ---------------------------------------------------------------------------
// fp32 vector GEMM (setup only): C[M,N] = A[M,K] @ B[K,N]
// ---------------------------------------------------------------------------
template<int BM,int BN,int BK,int TM,int TN>
__global__ __launch_bounds__((BM/TM)*(BN/TN))
void gemm_f32_nn(const float* __restrict__ A, const float* __restrict__ Bm,
                 float* __restrict__ C, int M, int N, int K) {
    constexpr int THREADS = (BM/TM)*(BN/TN);
    __shared__ float As[BK][BM+4];
    __shared__ float Bs[BK][BN+4];
    const int tid  = threadIdx.x;
    const int tcol = tid % (BN/TN);
    const int trow = tid / (BN/TN);
    const int bm   = blockIdx.y * BM;
    const int bn   = blockIdx.x * BN;
    float acc[TM][TN];
#pragma unroll
    for (int i = 0; i < TM; ++i)
#pragma unroll
        for (int j = 0; j < TN; ++j) acc[i][j] = 0.f;
    for (int k0 = 0; k0 < K; k0 += BK) {
#pragma unroll
        for (int r = 0; r < BM*BK/4; r += THREADS) {
            int i  = r + tid;
            int m  = i / (BK/4);
            int kk = (i % (BK/4)) * 4;
            const float4 v = *(const float4*)(&A[(size_t)(bm+m)*K + k0 + kk]);
            As[kk+0][m]=v.x; As[kk+1][m]=v.y; As[kk+2][m]=v.z; As[kk+3][m]=v.w;
        }
#pragma unroll
        for (int r = 0; r < BK*BN/4; r += THREADS) {
            int i  = r + tid;
            int kk = i / (BN/4);
            int n4 = (i % (BN/4)) * 4;
            const float4 v = *(const float4*)(&Bm[(size_t)(k0+kk)*N + bn + n4]);
            *(float4*)(&Bs[kk][n4]) = v;
        }
        __syncthreads();
#pragma unroll
        for (int k = 0; k < BK; ++k) {
            float a[TM], b[TN];
#pragma unroll
            for (int i = 0; i < TM; ++i) a[i] = As[k][trow*TM+i];
#pragma unroll
            for (int j = 0; j < TN; ++j) b[j] = Bs[k][tcol*TN+j];
#pragma unroll
            for (int i = 0; i < TM; ++i)
#pragma unroll
                for (int j = 0; j < TN; ++j) acc[i][j] += a[i]*b[j];
        }
        __syncthreads();
    }
#pragma unroll
    for (int i = 0; i < TM; ++i)
#pragma unroll
        for (int j = 0; j < TN; ++j)
            C[(size_t)(bm+trow*TM+i)*N + bn + tcol*TN + j] = acc[i][j];
}

// ---------------------------------------------------------------------------
// Weight swizzle to frag-major hi/lo, gate-interleaved columns.
// Output col n (0..4095): unit j=n>>2, gate q=n&3 -> source row q*1024 + j.
// K split: kf < kf0 from M0 (width K0), else from M1 (width K1).
// frag (cf, kf): dst[((cf*kfcnt+kf)*2+p)*512 + l*8 + j]  (cf = 16-col stripe)
// ---------------------------------------------------------------------------
__global__ void swz2(const float* __restrict__ M0, int K0, int kf0,
                     const float* __restrict__ M1, int K1, int kfcnt,
                     unsigned short* __restrict__ dst) {
    int gid = blockIdx.x * 256 + threadIdx.x;
    int l   = gid & 63;
    int kf  = (gid >> 6) % kfcnt;
    int cf  = gid / (64 * kfcnt);
    int n   = cf*16 + (l & 15);
    int row = ((n & 3) << 10) + (n >> 2);
    const float* src; int kk = (l >> 4) * 8;
    if (kf < kf0) { src = M0 + (size_t)row * K0; kk += kf * 32; }
    else          { src = M1 + (size_t)row * K1; kk += (kf - kf0) * 32; }
    short8v vh, vl;
#pragma unroll
    for (int j = 0; j < 8; ++j) {
        float f = src[kk + j];
        unsigned short h = bf16hi(f);
        vh[j] = (short)h;
        vl[j] = (short)bf16hi(f - bf2f(h));
    }
    size_t base = ((size_t)(cf * kfcnt + kf) * 2) * 512 + (size_t)l * 8;
    *(short8v*)(dst + base)       = vh;
    *(short8v*)(dst + base + 512) = vl;
}

// bcombI[4j+q] = b_ih0 + b_hh0 + W_ih0[row,:] . b_enc   (row = q*1024+j)
__global__ void build_bcombI(const float* __restrict__ W_ih0, const float* __restrict__ b_enc,
                             const float* __restrict__ b_ih0, const float* __restrict__ b_hh0,
                             float* __restrict__ bcombI) {
    int row  = blockIdx.x * 4 + (threadIdx.x >> 6);
    int lane = threadIdx.x & 63;
    const float* w = W_ih0 + (size_t)row * EMB;
    float s = 0.f;
    for (int k = lane; k < EMB; k += 64) s += w[k] * b_enc[k];
#pragma unroll
    for (int o = 32; o > 0; o >>= 1) s += __shfl_down(s, o);
    if (lane == 0) {
        int n = ((row & 1023) << 2) | (row >> 10);
        bcombI[n] = s + b_ih0[row] + b_hh0[row];
    }
}

__global__ void addvI(const float* __restrict__ a, const float* __restrict__ b,
                      float* __restrict__ o) {
    int i = blockIdx.x * 256 + threadIdx.x;
    int n = ((i & 1023) << 2) | (i >> 10);
    o[n] = a[i] + b[i];
}

// ---------------------------------------------------------------------------
// Persistent LSTM. 512 blocks x 256 threads (4 waves), 2 INDEPENDENT
// blocks/CU (no cross-block coupling) — when one block stalls at its
// barrier, the other issues: TLP across barrier domains.
// Decode: xcd=bid&7, u6=bid>>3 (0..63); u6<32 LEFT else RIGHT; v=u6&31;
//   cg = xcd*8+(v&7) (0..63), rg = v>>3 (0..3). Tile = 64 rows x 64 cols.
//   LEFT : gates0(t),   A cols 0..1535  (x_t|h0), 48 kf
//   RIGHT: gates1(t-1), A cols 512..2559 (h0|h1), 64 kf
// Waves = 4 col-quarters (cf=cg*4+w, 16 cols, full K): no K-reduction;
// each wave runs its own LSTM cell (4 units x 64 rows, c in regs).
// Pipeline (r5-proven): stage=2 kf, A global->reg->LDS dbuf (1 ahead),
// B global->reg (2 ahead), 1 barrier/stage.
// One grid barrier per phase; planes parity-double-buffered.
// ---------------------------------------------------------------------------
__device__ __forceinline__ void gridbar(unsigned* bar, unsigned target, int tid) {
    __syncthreads();
    if (tid == 0) {
        __threadfence();
        atomicAdd(bar, 1u);
        while (__hip_atomic_load(bar, __ATOMIC_RELAXED, __HIP_MEMORY_SCOPE_AGENT) < target)
            __builtin_amdgcn_s_sleep(1);
        __threadfence();
    }
    __syncthreads();
}

__device__ __forceinline__ void store_xz(unsigned short* ph, unsigned short* pl,
                                         int bid, int tid, float2 xv) {
    unsigned short h0 = bf16hi(xv.x), h1 = bf16hi(xv.y);
    ushort2 hh; hh.x = h0; hh.y = h1;
    ushort2 lv; lv.x = bf16hi(xv.x - bf2f(h0)); lv.y = bf16hi(xv.y - bf2f(h1));
    size_t o = (size_t)bid * PSTR + tid * 2;
    *(ushort2*)(ph + o) = hh;
    *(ushort2*)(pl + o) = lv;
}

__global__ __launch_bounds__(256, 2)
void lstm_persist(const float* __restrict__ x,
                  const unsigned short* __restrict__ WLz,
                  const unsigned short* __restrict__ WRz,
                  const float* __restrict__ biasLI, const float* __restrict__ biasRI,
                  unsigned short* __restrict__ p0h, unsigned short* __restrict__ p0l,
                  unsigned short* __restrict__ p1h, unsigned short* __restrict__ p1l,
                  const float* __restrict__ Wcls, const float* __restrict__ bcls,
                  float* __restrict__ out, unsigned* __restrict__ bar) {
    // A dbuf [buf2][seg16][64][8] shorts = 32 KB; per-wave gtile[64][20] overlays
    __shared__ unsigned short AslH[2][16][64][8];

    const int tid = threadIdx.x, bid = blockIdx.x;
    const int w = tid >> 6, l = tid & 63;
    const int xcd = bid & 7;
    const int u6 = bid >> 3;                 // 0..63
    const bool is_left = (u6 < 32);
    const int v = u6 & 31;
    const int cg = xcd * 8 + (v & 7);        // 0..63
    const int rg = v >> 3;                   // 0..3
    const int KF = is_left ? 48 : 64;
    const int NS = KF >> 1;                  // stages of 2 kf
    const int acol0 = is_left ? 0 : 512;
    const int hcol0 = is_left ? 512 : 1536;
    const int r0 = rg * 64;
    const unsigned short* Bz = is_left ? WLz : WRz;
    const float* biasI = is_left ? biasLI : biasRI;
    const int cf = cg * 4 + w;               // this wave's 16-col fragment
    const unsigned short* bp = Bz + ((size_t)cf * KF) * 1024 + (size_t)l * 8;
    const float biasv = biasI[cf*16 + (l & 15)];

    unsigned short* PH[2] = {p0h, p1h};
    unsigned short* PL[2] = {p0l, p1l};

    float cst[4] = {0.f, 0.f, 0.f, 0.f};
    const int cu = l & 3, rq = l >> 2;       // cell: unit cu, rows rq*4..+3

    unsigned target = 0;

    if (bid < B_SZ) {   // stage x(0) into plane 0 (bid == batch row)
        float2 xv = *(const float2*)&x[((size_t)bid * T_SZ) * IN_DIM + tid * 2];
        store_xz(p0h, p0l, bid, tid, xv);
    }
    target += NBLK; gridbar(bar, target, tid);

    for (int t = 0; t <= T_SZ; ++t) {
        const int cur = t & 1, nxt = cur ^ 1;
        const bool conv = (t < T_SZ - 1) && (bid < B_SZ);
        float2 xv;
        if (conv) xv = *(const float2*)&x[((size_t)bid * T_SZ + t + 1) * IN_DIM + tid * 2];

        const bool active = is_left ? (t < T_SZ) : (t >= 1);
        if (active) {
            const unsigned short* ph  = PH[cur];
            const unsigned short* plo = PL[cur];

            auto loadA = [&](int s, short8v (&r)[4]) {
#pragma unroll
                for (int i = 0; i < 4; ++i) {
                    int seg = w*4 + i;               // kf2=seg>>3, mf=(seg>>1)&3, pl=seg&1
                    int kf2 = seg >> 3, mf = (seg >> 1) & 3, pl = seg & 1;
                    const unsigned short* p = pl ? plo : ph;
                    size_t o = (size_t)(r0 + mf*16 + (l & 15)) * PSTR
                             + acol0 + (s*2 + kf2)*32 + ((l >> 4) * 8);
                    r[i] = *(const short8v*)(p + o);
                }
            };
            auto writeA = [&](int buf, short8v (&r)[4]) {
#pragma unroll
                for (int i = 0; i < 4; ++i) {
                    int seg = w*4 + i;
                    *(short8v*)&AslH[buf][seg][l][0] = r[i];
                }
            };
            auto loadB = [&](int s, short8v (&b)[4]) {
#pragma unroll
                for (int k2 = 0; k2 < 2; ++k2) {
                    const unsigned short* q = bp + (size_t)(s*2 + k2) * 1024;
                    b[k2*2+0] = *(const short8v*)q;
                    b[k2*2+1] = *(const short8v*)(q + 512);
                }
            };

            floatx4 acc[4];
#pragma unroll
            for (int m = 0; m < 4; ++m) acc[m] = (floatx4){biasv, biasv, biasv, biasv};

            auto mfmaStage = [&](int buf, short8v (&b)[4]) {
#pragma unroll
                for (int k2 = 0; k2 < 2; ++k2) {
                    short8v ah[4], al[4];
#pragma unroll
                    for (int mf = 0; mf < 4; ++mf) {
                        ah[mf] = *(const short8v*)&AslH[buf][k2*8 + mf*2 + 0][l][0];
                        al[mf] = *(const short8v*)&AslH[buf][k2*8 + mf*2 + 1][l][0];
                    }
                    __builtin_amdgcn_s_setprio(1);
#pragma unroll
                    for (int mf = 0; mf < 4; ++mf) {
                        acc[mf] = __builtin_amdgcn_mfma_f32_16x16x32_bf16(ah[mf], b[k2*2+0], acc[mf], 0, 0, 0);
                        acc[mf] = __builtin_amdgcn_mfma_f32_16x16x32_bf16(ah[mf], b[k2*2+1], acc[mf], 0, 0, 0);
                        acc[mf] = __builtin_amdgcn_mfma_f32_16x16x32_bf16(al[mf], b[k2*2+0], acc[mf], 0, 0, 0);
                    }
                    __builtin_amdgcn_s_setprio(0);
                }
            };

            short8v rA[4], rB[4], bE[4], bO[4];
            loadA(0, rA); loadB(0, bE);
            loadA(1, rB); loadB(1, bO);
            writeA(0, rA);
            __syncthreads();

            for (int s = 0; s < NS; s += 2) {
                // even stage s: compute buf0; write A(s+1)->buf1
                if (s + 2 < NS) loadA(s + 2, rA);
                writeA(1, rB);
                mfmaStage(0, bE);
                if (s + 2 < NS) loadB(s + 2, bE);
                __syncthreads();
                // odd stage s+1: compute buf1; write A(s+2)->buf0
                if (s + 3 < NS) loadA(s + 3, rB);
                if (s + 2 < NS) writeA(0, rA);
                mfmaStage(1, bO);
                if (s + 3 < NS) loadB(s + 3, bO);
                __syncthreads();
            }

            // per-wave gate tile (overlays A dbuf; all K-reads done at last sync)
            float (*gt)[20] = (float (*)[20])((float*)AslH + (size_t)w * 64 * 20);
#pragma unroll
            for (int mf = 0; mf < 4; ++mf) {
                int rb = mf*16 + ((l >> 4) * 4);
#pragma unroll
                for (int j = 0; j < 4; ++j)
                    gt[rb + j][l & 15] = acc[mf][j];
            }
            __syncthreads();

            // LSTM cell: wave-local, 4 units x 64 rows, 4 cells/lane, c in regs
            {
                unsigned short* nh = PH[nxt];
                unsigned short* nl = PL[nxt];
#pragma unroll
                for (int i = 0; i < 4; ++i) {
                    int r = rq*4 + i;
                    float4 g = *(const float4*)&gt[r][cu*4];
                    float ii = 1.f / (1.f + expf(-g.x));
                    float ff = 1.f / (1.f + expf(-g.y));
                    float gg = tanhf(g.z);
                    float oo = 1.f / (1.f + expf(-g.w));
                    float cn = ff * cst[i] + ii * gg;
                    cst[i] = cn;
                    float h = oo * tanhf(cn);
                    unsigned short hh = bf16hi(h);
                    size_t o = (size_t)(r0 + r) * PSTR + hcol0 + cf*4 + cu;
                    nh[o] = hh;
                    nl[o] = bf16hi(h - bf2f(hh));
                }
            }
        }

        if (conv) store_xz(PH[nxt], PL[nxt], bid, tid, xv);
        target += NBLK; gridbar(bar, target, tid);
    }

    // classifier: blocks 0..255 -> batch row bid; h1 = plane[(T+1)&1]
    if (bid < B_SZ) {
        const unsigned short* hh = ((T_SZ + 1) & 1) ? p1h : p0h;
        const unsigned short* hl = ((T_SZ + 1) & 1) ? p1l : p0l;
        float part[NCLS];
#pragma unroll
        for (int n = 0; n < NCLS; ++n) part[n] = 0.f;
        for (int k = tid; k < HID; k += 256) {
            size_t o = (size_t)bid * PSTR + 1536 + k;
            float hv = bf2f(hh[o]) + bf2f(hl[o]);
#pragma unroll
            for (int n = 0; n < NCLS; ++n) part[n] += hv * Wcls[(size_t)n * HID + k];
        }
        float* red = (float*)AslH;
        for (int n = 0; n < NCLS; ++n) {
            red[tid] = part[n];
            __syncthreads();
            for (int s = 128; s > 0; s >>= 1) {
                if (tid < s) red[tid] += red[tid + s];
                __syncthreads();
            }
            if (tid == 0) out[(size_t)bid * NCLS + n] = red[0] + bcls[n];
            __syncthreads();
        }
    }
}

extern "C" void kernel_launch(void* const* d_in, const int* in_sizes, int n_in,
                              void* d_out, int out_size, void* d_ws, size_t ws_size,
                              hipStream_t stream) {
    const float* x      = (const float*)d_in[0];
    const float* W_enc  = (const float*)d_in[1];
    const float* b_enc  = (const float*)d_in[2];
    const float* W_ih0  = (const float*)d_in[3];
    const float* W_hh0  = (const float*)d_in[4];
    const float* b_ih0  = (const float*)d_in[5];
    const float* b_hh0  = (const float*)d_in[6];
    const float* W_ih1  = (const float*)d_in[7];
    const float* W_hh1  = (const float*)d_in[8];
    const float* b_ih1  = (const float*)d_in[9];
    const float* b_hh1  = (const float*)d_in[10];
    const float* W_cls  = (const float*)d_in[11];
    const float* b_cls  = (const float*)d_in[12];
    float* out = (float*)d_out;

    float* ws = (float*)d_ws;
    size_t off = 0;
    unsigned short* WLz    = (unsigned short*)(ws + off); off += (size_t)G4 * 1536 * 2 / 2;
    unsigned short* WRz    = (unsigned short*)(ws + off); off += (size_t)G4 * 2048 * 2 / 2;
    float*          Wcomb  = ws + off;                    off += (size_t)G4 * IN_DIM;
    float*          biasLI = ws + off;                    off += G4;
    float*          biasRI = ws + off;                    off += G4;
    unsigned short* planes = (unsigned short*)(ws + off); off += (size_t)4 * B_SZ * PSTR / 2;
    unsigned*       bar    = (unsigned*)(ws + off);       off += 64;

    unsigned short* p0h = planes;
    unsigned short* p0l = p0h + (size_t)B_SZ * PSTR;
    unsigned short* p1h = p0l + (size_t)B_SZ * PSTR;
    unsigned short* p1l = p1h + (size_t)B_SZ * PSTR;

    // --- setup ---
    gemm_f32_nn<128,128,16,8,8><<<dim3(IN_DIM/128, G4/128), 256, 0, stream>>>(
        W_ih0, W_enc, Wcomb, G4, IN_DIM, EMB);
    build_bcombI<<<G4/4, 256, 0, stream>>>(W_ih0, b_enc, b_ih0, b_hh0, biasLI);
    addvI<<<G4/256, 256, 0, stream>>>(b_ih1, b_hh1, biasRI);
    // WLz: [Wcomb(16 kf) | W_hh0(32 kf)] ; WRz: [W_ih1(32 kf) | W_hh1(32 kf)]
    swz2<<<64*48, 256, 0, stream>>>(Wcomb, IN_DIM, 16, W_hh0, HID, 48, WLz);
    swz2<<<64*64, 256, 0, stream>>>(W_ih1, HID, 32, W_hh1, HID, 64, WRz);
    hipMemsetAsync(planes, 0, (size_t)4 * B_SZ * PSTR * 2, stream);
    hipMemsetAsync(bar, 0, 64 * sizeof(unsigned), stream);

    // --- the whole recurrence in one kernel ---
    lstm_persist<<<NBLK, 256, 0, stream>>>(
        x, WLz, WRz, biasLI, biasRI,
        p0h, p0l, p1h, p1l, W_cls, b_cls, out, bar);
}

// Round 13
// 11668.757 us; speedup vs baseline: 2.0918x; 1.0672x over previous
//
#include <hip/hip_runtime.h>

#define B_SZ   256
#define T_SZ   128
#define IN_DIM 512
#define EMB    1024
#define HID    1024
#define G4     4096
#define NCLS   10
#define PSTR   2560   // A-plane row stride (shorts): [x 512 | h0 1024 | h1 1024]
#define NBLK   256    // 256 blocks x 512 threads (8 waves), 1 block/CU

typedef __attribute__((ext_vector_type(8))) short short8v;
typedef __attribute__((ext_vector_type(4))) float floatx4;

__device__ __forceinline__ unsigned short bf16hi(float f) {
    union { float f; unsigned u; } v; v.f = f;
    unsigned r = v.u + 0x7fff + ((v.u >> 16) & 1);   // RNE
    return (unsigned short)(r >> 16);
}
__device__ __forceinline__ float bf2f(unsigned short b) {
    union { unsigned u; float f; } v; v.u = ((unsigned)b) << 16;
    return v.f;
}

// ---------------------------------------------------------------------------
// fp32 vector GEMM (setup only): C[M,N] = A[M,K] @ B[K,N]
// ---------------------------------------------------------------------------
template<int BM,int BN,int BK,int TM,int TN>
__global__ __launch_bounds__((BM/TM)*(BN/TN))
void gemm_f32_nn(const float* __restrict__ A, const float* __restrict__ Bm,
                 float* __restrict__ C, int M, int N, int K) {
    constexpr int THREADS = (BM/TM)*(BN/TN);
    __shared__ float As[BK][BM+4];
    __shared__ float Bs[BK][BN+4];
    const int tid  = threadIdx.x;
    const int tcol = tid % (BN/TN);
    const int trow = tid / (BN/TN);
    const int bm   = blockIdx.y * BM;
    const int bn   = blockIdx.x * BN;
    float acc[TM][TN];
#pragma unroll
    for (int i = 0; i < TM; ++i)
#pragma unroll
        for (int j = 0; j < TN; ++j) acc[i][j] = 0.f;
    for (int k0 = 0; k0 < K; k0 += BK) {
#pragma unroll
        for (int r = 0; r < BM*BK/4; r += THREADS) {
            int i  = r + tid;
            int m  = i / (BK/4);
            int kk = (i % (BK/4)) * 4;
            const float4 v = *(const float4*)(&A[(size_t)(bm+m)*K + k0 + kk]);
            As[kk+0][m]=v.x; As[kk+1][m]=v.y; As[kk+2][m]=v.z; As[kk+3][m]=v.w;
        }
#pragma unroll
        for (int r = 0; r < BK*BN/4; r += THREADS) {
            int i  = r + tid;
            int kk = i / (BN/4);
            int n4 = (i % (BN/4)) * 4;
            const float4 v = *(const float4*)(&Bm[(size_t)(k0+kk)*N + bn + n4]);
            *(float4*)(&Bs[kk][n4]) = v;
        }
        __syncthreads();
#pragma unroll
        for (int k = 0; k < BK; ++k) {
            float a[TM], b[TN];
#pragma unroll
            for (int i = 0; i < TM; ++i) a[i] = As[k][trow*TM+i];
#pragma unroll
            for (int j = 0; j < TN; ++j) b[j] = Bs[k][tcol*TN+j];
#pragma unroll
            for (int i = 0; i < TM; ++i)
#pragma unroll
                for (int j = 0; j < TN; ++j) acc[i][j] += a[i]*b[j];
        }
        __syncthreads();
    }
#pragma unroll
    for (int i = 0; i < TM; ++i)
#pragma unroll
        for (int j = 0; j < TN; ++j)
            C[(size_t)(bm+trow*TM+i)*N + bn + tcol*TN + j] = acc[i][j];
}

// ---------------------------------------------------------------------------
// Weight swizzle to frag-major hi/lo, gate-interleaved columns.
// Output col n (0..4095): unit j=n>>2, gate q=n&3 -> source row q*1024 + j.
// K split: kf < kf0 from M0 (width K0), else from M1 (width K1).
// frag (cf, kf): dst[((cf*kfcnt+kf)*2+p)*512 + l*8 + j]  (cf = 16-col stripe)
// ---------------------------------------------------------------------------
__global__ void swz2(const float* __restrict__ M0, int K0, int kf0,
                     const float* __restrict__ M1, int K1, int kfcnt,
                     unsigned short* __restrict__ dst) {
    int gid = blockIdx.x * 256 + threadIdx.x;
    int l   = gid & 63;
    int kf  = (gid >> 6) % kfcnt;
    int cf  = gid / (64 * kfcnt);
    int n   = cf*16 + (l & 15);
    int row = ((n & 3) << 10) + (n >> 2);
    const float* src; int kk = (l >> 4) * 8;
    if (kf < kf0) { src = M0 + (size_t)row * K0; kk += kf * 32; }
    else          { src = M1 + (size_t)row * K1; kk += (kf - kf0) * 32; }
    short8v vh, vl;
#pragma unroll
    for (int j = 0; j < 8; ++j) {
        float f = src[kk + j];
        unsigned short h = bf16hi(f);
        vh[j] = (short)h;
        vl[j] = (short)bf16hi(f - bf2f(h));
    }
    size_t base = ((size_t)(cf * kfcnt + kf) * 2) * 512 + (size_t)l * 8;
    *(short8v*)(dst + base)       = vh;
    *(short8v*)(dst + base + 512) = vl;
}

// bcombI[4j+q] = b_ih0 + b_hh0 + W_ih0[row,:] . b_enc   (row = q*1024+j)
__global__ void build_bcombI(const float* __restrict__ W_ih0, const float* __restrict__ b_enc,
                             const float* __restrict__ b_ih0, const float* __restrict__ b_hh0,
                             float* __restrict__ bcombI) {
    int row  = blockIdx.x * 4 + (threadIdx.x >> 6);
    int lane = threadIdx.x & 63;
    const float* w = W_ih0 + (size_t)row * EMB;
    float s = 0.f;
    for (int k = lane; k < EMB; k += 64) s += w[k] * b_enc[k];
#pragma unroll
    for (int o = 32; o > 0; o >>= 1) s += __shfl_down(s, o);
    if (lane == 0) {
        int n = ((row & 1023) << 2) | (row >> 10);
        bcombI[n] = s + b_ih0[row] + b_hh0[row];
    }
}

__global__ void addvI(const float* __restrict__ a, const float* __restrict__ b,
                      float* __restrict__ o) {
    int i = blockIdx.x * 256 + threadIdx.x;
    int n = ((i & 1023) << 2) | (i >> 10);
    o[n] = a[i] + b[i];
}

// ---------------------------------------------------------------------------
// Persistent LSTM, 3-pass split-bf16, BARRIER-FREE register-pipelined K-loop.
// 256 blocks x 512 threads (8 waves), 1 block/CU, launch_bounds(512,1) so the
// 2-deep slice pipeline (~160 VGPR) register-allocates (r6 failed at cap 128).
// XCD-dedup decode: xcd=bid&7, idx=bid>>3; idx<16 LEFT else RIGHT;
//   cgl=xcd*8+(i2&7), rg=i2>>3. LEFT: gates0(t), A cols 0..1535, 48 kf.
//   RIGHT: gates1(t-1), A cols 512..2559, 64 kf.
// 8 waves = 2 kgrp (K-halves) x 2 rowhalf x 2 colhalf. Per kf per wave:
// 8 A-loads (64 rows, hi/lo) + 4 B-loads global->reg, 24 MFMA (setprio).
// No LDS, no syncthreads until the gtile reduce; waves free-run their K-range
// with compiler-counted vmcnt. Epilogue: kgrp partial-sum via gtile
// (conflict-free), LSTM cell (c in regs). One grid barrier per phase.
// ---------------------------------------------------------------------------
__device__ __forceinline__ void gridbar(unsigned* bar, unsigned target, int tid) {
    __syncthreads();
    if (tid == 0) {
        __threadfence();
        atomicAdd(bar, 1u);
        while (__hip_atomic_load(bar, __ATOMIC_RELAXED, __HIP_MEMORY_SCOPE_AGENT) < target)
            __builtin_amdgcn_s_sleep(1);
        __threadfence();
    }
    __syncthreads();
}

__device__ __forceinline__ void store_xz(unsigned short* ph, unsigned short* pl,
                                         int bid, int tid, float2 xv) {
    unsigned short h0 = bf16hi(xv.x), h1 = bf16hi(xv.y);
    ushort2 hh; hh.x = h0; hh.y = h1;
    ushort2 lv; lv.x = bf16hi(xv.x - bf2f(h0)); lv.y = bf16hi(xv.y - bf2f(h1));
    size_t o = (size_t)bid * PSTR + tid * 2;
    *(ushort2*)(ph + o) = hh;
    *(ushort2*)(pl + o) = lv;
}

struct Slice {
    short8v ah[4], al[4];    // A: 4 mf x hi/lo (this wave's 64 rows)
    short8v b[4];            // B: 2 cf x hi/lo
};

__global__ __launch_bounds__(512, 1)
void lstm_persist(const float* __restrict__ x,
                  const unsigned short* __restrict__ WLz,
                  const unsigned short* __restrict__ WRz,
                  const float* __restrict__ biasLI, const float* __restrict__ biasRI,
                  unsigned short* __restrict__ p0h, unsigned short* __restrict__ p0l,
                  unsigned short* __restrict__ p1h, unsigned short* __restrict__ p1l,
                  const float* __restrict__ Wcls, const float* __restrict__ bcls,
                  float* __restrict__ out, unsigned* __restrict__ bar) {
    __shared__ float gtile[128][68];                 // 34.8 KB, conflict-light

    const int tid = threadIdx.x, bid = blockIdx.x;
    const int w = tid >> 6, l = tid & 63;
    const int kgrp = w >> 2, sub = w & 3;
    const int rowhalf = sub & 1, colhalf = sub >> 1;
    // XCD-dedup block map (bijective)
    const int xcd = bid & 7;
    const int idx = bid >> 3;
    const bool is_left = (idx < 16);
    const int i2 = is_left ? idx : idx - 16;
    const int cgl = xcd * 8 + (i2 & 7);
    const int rg  = i2 >> 3;
    const int kfcnt = is_left ? 48 : 64;
    const int SMAXH = kfcnt >> 1;            // kf per kgroup
    const int acol0 = is_left ? 0 : 512;
    const int hcol0 = is_left ? 512 : 1536;
    const int r0 = rg * 128;
    const unsigned short* Bz = is_left ? WLz : WRz;
    const float* biasI = is_left ? biasLI : biasRI;
    const int kf_base = kgrp * SMAXH;

    const int cf0 = cgl*4 + colhalf*2;
    const unsigned short* bp0 = Bz + ((size_t)cf0     * kfcnt) * 1024 + (size_t)l * 8;
    const unsigned short* bp1 = Bz + ((size_t)(cf0+1) * kfcnt) * 1024 + (size_t)l * 8;

    float bias0 = 0.f, bias1 = 0.f;
    if (kgrp == 0) {
        int cA = cgl*64 + colhalf*32 + (l & 15);
        bias0 = biasI[cA]; bias1 = biasI[cA + 16];
    }

    unsigned short* PH[2] = {p0h, p1h};
    unsigned short* PL[2] = {p0l, p1l};

    float cst[4] = {0.f, 0.f, 0.f, 0.f};

    unsigned target = 0;

    if (tid < 256) {   // stage x(0) into plane 0 (bid == batch row)
        float2 xv = *(const float2*)&x[((size_t)bid * T_SZ) * IN_DIM + tid * 2];
        store_xz(p0h, p0l, bid, tid, xv);
    }
    target += NBLK; gridbar(bar, target, tid);

    for (int t = 0; t <= T_SZ; ++t) {
        const int cur = t & 1, nxt = cur ^ 1;
        const bool conv = (t < T_SZ - 1) && (tid < 256);
        float2 xv;
        if (conv) xv = *(const float2*)&x[((size_t)bid * T_SZ + t + 1) * IN_DIM + tid * 2];

        const bool active = is_left ? (t < T_SZ) : (t >= 1);
        if (active) {
            const unsigned short* ph  = PH[cur];
            const unsigned short* plo = PL[cur];

            auto loadS = [&](int s, Slice& S) {
                const int kf = kf_base + s;
                const size_t ko = (size_t)acol0 + (size_t)kf * 32 + ((l >> 4) * 8);
#pragma unroll
                for (int mf = 0; mf < 4; ++mf) {
                    size_t o = (size_t)(r0 + rowhalf*64 + mf*16 + (l & 15)) * PSTR + ko;
                    S.ah[mf] = *(const short8v*)(ph + o);
                    S.al[mf] = *(const short8v*)(plo + o);
                }
                const unsigned short* q0 = bp0 + (size_t)kf * 1024;
                const unsigned short* q1 = bp1 + (size_t)kf * 1024;
                S.b[0] = *(const short8v*)q0; S.b[1] = *(const short8v*)(q0 + 512);
                S.b[2] = *(const short8v*)q1; S.b[3] = *(const short8v*)(q1 + 512);
            };

            floatx4 acc[4][2];
#pragma unroll
            for (int m = 0; m < 4; ++m) {
                acc[m][0] = (floatx4){bias0, bias0, bias0, bias0};
                acc[m][1] = (floatx4){bias1, bias1, bias1, bias1};
            }

            auto compute = [&](Slice& S) {
                __builtin_amdgcn_s_setprio(1);
#pragma unroll
                for (int m = 0; m < 4; ++m) {
                    acc[m][0] = __builtin_amdgcn_mfma_f32_16x16x32_bf16(S.ah[m], S.b[0], acc[m][0], 0, 0, 0);
                    acc[m][0] = __builtin_amdgcn_mfma_f32_16x16x32_bf16(S.ah[m], S.b[1], acc[m][0], 0, 0, 0);
                    acc[m][0] = __builtin_amdgcn_mfma_f32_16x16x32_bf16(S.al[m], S.b[0], acc[m][0], 0, 0, 0);
                    acc[m][1] = __builtin_amdgcn_mfma_f32_16x16x32_bf16(S.ah[m], S.b[2], acc[m][1], 0, 0, 0);
                    acc[m][1] = __builtin_amdgcn_mfma_f32_16x16x32_bf16(S.ah[m], S.b[3], acc[m][1], 0, 0, 0);
                    acc[m][1] = __builtin_amdgcn_mfma_f32_16x16x32_bf16(S.al[m], S.b[2], acc[m][1], 0, 0, 0);
                }
                __builtin_amdgcn_s_setprio(0);
            };

            Slice S0, S1;
            loadS(0, S0);
            loadS(1, S1);
            for (int s = 0; s < SMAXH; s += 2) {
                compute(S0);
                if (s + 2 < SMAXH) loadS(s + 2, S0);
                compute(S1);
                if (s + 3 < SMAXH) loadS(s + 3, S1);
            }

            // kgroup partial-sum via gtile (conflict-free layout, r11-proven)
            if (kgrp == 0) {
#pragma unroll
                for (int m = 0; m < 4; ++m)
#pragma unroll
                    for (int c = 0; c < 2; ++c) {
                        int col = colhalf*32 + c*16 + (l & 15);
#pragma unroll
                        for (int jj = 0; jj < 4; ++jj)
                            gtile[rowhalf*64 + m*16 + ((l >> 4)*4) + jj][col] = acc[m][c][jj];
                    }
            }
            __syncthreads();
            if (kgrp == 1) {
#pragma unroll
                for (int m = 0; m < 4; ++m)
#pragma unroll
                    for (int c = 0; c < 2; ++c) {
                        int col = colhalf*32 + c*16 + (l & 15);
#pragma unroll
                        for (int jj = 0; jj < 4; ++jj)
                            gtile[rowhalf*64 + m*16 + ((l >> 4)*4) + jj][col] += acc[m][c][jj];
                    }
            }
            __syncthreads();

            // LSTM cell: 16 units x 128 rows, 4 cells/thread, c-state in regs
            {
                int u = tid & 15, rq = tid >> 4;
                unsigned short* nh = PH[nxt];
                unsigned short* nl = PL[nxt];
#pragma unroll
                for (int i = 0; i < 4; ++i) {
                    int r = rq*4 + i;
                    float4 gq = *(const float4*)&gtile[r][4*u];
                    float ii = 1.f / (1.f + expf(-gq.x));
                    float ff = 1.f / (1.f + expf(-gq.y));
                    float gg = tanhf(gq.z);
                    float oo = 1.f / (1.f + expf(-gq.w));
                    float cn = ff * cst[i] + ii * gg;
                    cst[i] = cn;
                    float h = oo * tanhf(cn);
                    unsigned short hh = bf16hi(h);
                    size_t o = (size_t)(r0 + r) * PSTR + hcol0 + cgl*16 + u;
                    nh[o] = hh;
                    nl[o] = bf16hi(h - bf2f(hh));
                }
            }
        }

        if (conv) store_xz(PH[nxt], PL[nxt], bid, tid, xv);
        target += NBLK; gridbar(bar, target, tid);
    }

    // classifier: block bid -> batch row bid; h1 = plane[(T+1)&1] cols 1536..2559
    {
        const unsigned short* hh = PH[(T_SZ + 1) & 1];
        const unsigned short* hl = PL[(T_SZ + 1) & 1];
        float part[NCLS];
#pragma unroll
        for (int n = 0; n < NCLS; ++n) part[n] = 0.f;
        for (int k = tid; k < HID; k += 512) {
            size_t o = (size_t)bid * PSTR + 1536 + k;
            float hv = bf2f(hh[o]) + bf2f(hl[o]);
#pragma unroll
            for (int n = 0; n < NCLS; ++n) part[n] += hv * Wcls[(size_t)n * HID + k];
        }
        float* red = (float*)gtile;
        for (int n = 0; n < NCLS; ++n) {
            red[tid] = part[n];
            __syncthreads();
            for (int s = 256; s > 0; s >>= 1) {
                if (tid < s) red[tid] += red[tid + s];
                __syncthreads();
            }
            if (tid == 0) out[(size_t)bid * NCLS + n] = red[0] + bcls[n];
            __syncthreads();
        }
    }
}

extern "C" void kernel_launch(void* const* d_in, const int* in_sizes, int n_in,
                              void* d_out, int out_size, void* d_ws, size_t ws_size,
                              hipStream_t stream) {
    const float* x      = (const float*)d_in[0];
    const float* W_enc  = (const float*)d_in[1];
    const float* b_enc  = (const float*)d_in[2];
    const float* W_ih0  = (const float*)d_in[3];
    const float* W_hh0  = (const float*)d_in[4];
    const float* b_ih0  = (const float*)d_in[5];
    const float* b_hh0  = (const float*)d_in[6];
    const float* W_ih1  = (const float*)d_in[7];
    const float* W_hh1  = (const float*)d_in[8];
    const float* b_ih1  = (const float*)d_in[9];
    const float* b_hh1  = (const float*)d_in[10];
    const float* W_cls  = (const float*)d_in[11];
    const float* b_cls  = (const float*)d_in[12];
    float* out = (float*)d_out;

    float* ws = (float*)d_ws;
    size_t off = 0;
    unsigned short* WLz    = (unsigned short*)(ws + off); off += (size_t)G4 * 1536 * 2 / 2;
    unsigned short* WRz    = (unsigned short*)(ws + off); off += (size_t)G4 * 2048 * 2 / 2;
    float*          Wcomb  = ws + off;                    off += (size_t)G4 * IN_DIM;
    float*          biasLI = ws + off;                    off += G4;
    float*          biasRI = ws + off;                    off += G4;
    unsigned short* planes = (unsigned short*)(ws + off); off += (size_t)4 * B_SZ * PSTR / 2;
    unsigned*       bar    = (unsigned*)(ws + off);       off += 64;

    unsigned short* p0h = planes;
    unsigned short* p0l = p0h + (size_t)B_SZ * PSTR;
    unsigned short* p1h = p0l + (size_t)B_SZ * PSTR;
    unsigned short* p1l = p1h + (size_t)B_SZ * PSTR;

    // --- setup ---
    gemm_f32_nn<128,128,16,8,8><<<dim3(IN_DIM/128, G4/128), 256, 0, stream>>>(
        W_ih0, W_enc, Wcomb, G4, IN_DIM, EMB);
    build_bcombI<<<G4/4, 256, 0, stream>>>(W_ih0, b_enc, b_ih0, b_hh0, biasLI);
    addvI<<<G4/256, 256, 0, stream>>>(b_ih1, b_hh1, biasRI);
    // WLz: [Wcomb(16 kf) | W_hh0(32 kf)] ; WRz: [W_ih1(32 kf) | W_hh1(32 kf)]
    swz2<<<64*48, 256, 0, stream>>>(Wcomb, IN_DIM, 16, W_hh0, HID, 48, WLz);
    swz2<<<64*64, 256, 0, stream>>>(W_ih1, HID, 32, W_hh1, HID, 64, WRz);
    hipMemsetAsync(planes, 0, (size_t)4 * B_SZ * PSTR * 2, stream);
    hipMemsetAsync(bar, 0, 64 * sizeof(unsigned), stream);

    // --- the whole recurrence in one kernel ---
    lstm_persist<<<NBLK, 512, 0, stream>>>(
        x, WLz, WRz, biasLI, biasRI,
        p0h, p0l, p1h, p1l, W_cls, b_cls, out, bar);
}